// Round 6
// baseline (112.701 us; speedup 1.0000x reference)
//
#include <hip/hip_runtime.h>
#include <hip/hip_bf16.h>

typedef _Float16 h2 __attribute__((ext_vector_type(2)));

constexpr int kB = 4, kN = 256, kC = 256, kH = 8, kF = 64, kHF = 512;
constexpr int kIPB = 4;   // attention rows (i) per block
constexpr int kJS = 2;    // j-split factor (blocks per row-group)

union H2U { h2 h; unsigned int u; };

// ---------------------------------------------------------------------------
// Phase A: g = x @ W  (fp32 in, f16 out to ws). W selected by blockIdx.y.
// Also zeroes d_out (y==0 blocks) so the attention kernel can atomicAdd.
// Block: 256 threads, 4 rows x 512 cols. Grid: (256, 2).
// ---------------------------------------------------------------------------
__global__ __launch_bounds__(256) void gat_gemm_kernel(
    const float* __restrict__ x,
    const float* __restrict__ Wl,
    const float* __restrict__ Wr,
    unsigned int* __restrict__ gl,    // f16 pairs
    unsigned int* __restrict__ gr,
    float* __restrict__ out)
{
    __shared__ float xs[4][kC];   // 4 KiB
    const int rowBase = blockIdx.x * 4;
    const float* Wm = (blockIdx.y == 0) ? Wl : Wr;
    unsigned int* gout = (blockIdx.y == 0) ? gl : gr;

    const int tid = threadIdx.x;

    // zero d_out: 256 blocks x 256 thr x 2 float4 = 524288 floats
    if (blockIdx.y == 0) {
        float4 z = make_float4(0.f, 0.f, 0.f, 0.f);
        float4* o = (float4*)out + blockIdx.x * 512 + tid * 2;
        o[0] = z; o[1] = z;
    }

    // Stage 4 rows of x into LDS (256 thr x 4 floats = 1024).
    {
        const int r = tid >> 6;
        const int kc = (tid & 63) * 4;
        *(float4*)&xs[r][kc] = *(const float4*)(x + (rowBase + r) * kC + kc);
    }
    __syncthreads();

    const int c0 = tid * 2;           // two adjacent output cols
    float acc[4][2];
#pragma unroll
    for (int r = 0; r < 4; ++r) { acc[r][0] = 0.f; acc[r][1] = 0.f; }

    // software pipeline: preload next k-step's W
    float2 wv[4], wn[4];
#pragma unroll
    for (int kk = 0; kk < 4; ++kk)
        wv[kk] = *(const float2*)(Wm + kk * kHF + c0);

    for (int k = 0; k < kC; k += 4) {
        if (k + 4 < kC) {
#pragma unroll
            for (int kk = 0; kk < 4; ++kk)
                wn[kk] = *(const float2*)(Wm + (k + 4 + kk) * kHF + c0);
        }
#pragma unroll
        for (int r = 0; r < 4; ++r) {
            float4 xv = *(const float4*)&xs[r][k];
            acc[r][0] = fmaf(xv.x, wv[0].x, acc[r][0]);
            acc[r][1] = fmaf(xv.x, wv[0].y, acc[r][1]);
            acc[r][0] = fmaf(xv.y, wv[1].x, acc[r][0]);
            acc[r][1] = fmaf(xv.y, wv[1].y, acc[r][1]);
            acc[r][0] = fmaf(xv.z, wv[2].x, acc[r][0]);
            acc[r][1] = fmaf(xv.z, wv[2].y, acc[r][1]);
            acc[r][0] = fmaf(xv.w, wv[3].x, acc[r][0]);
            acc[r][1] = fmaf(xv.w, wv[3].y, acc[r][1]);
        }
#pragma unroll
        for (int kk = 0; kk < 4; ++kk) wv[kk] = wn[kk];
    }

#pragma unroll
    for (int r = 0; r < 4; ++r) {
        H2U p; p.h = (h2){(_Float16)acc[r][0], (_Float16)acc[r][1]};
        gout[((rowBase + r) * kHF + c0) >> 1] = p.u;
    }
}

// ---------------------------------------------------------------------------
// Phase B: fused leaky-dot / head-softmax / aggregation, f16 math.
// Grid (256, 2): x -> 4 consecutive (b,i) rows, y -> j-half [0,128)/[128,256).
// Block = 1024 threads (16 waves); 2 blocks/CU = 8 waves/SIMD (VGPR<=64).
// lane = h*8+fg. adj pre-packed to 1-bit masks in LDS (1 uint per j = 4 ii
// bytes x 8 h bits) -> main loop has zero global adj loads.
// Partial outputs combined across the 2 j-half blocks via fp32 atomicAdd
// (out zeroed by the GEMM kernel).
// ---------------------------------------------------------------------------
__global__ __launch_bounds__(1024, 8) void gat_attn_kernel(
    const unsigned int* __restrict__ gl,   // f16 pairs
    const unsigned int* __restrict__ gr,
    const float* __restrict__ attn_w,
    const int* __restrict__ adj,
    float* __restrict__ out)
{
    __shared__ float red[8 * kIPB * kHF];  // 64 KiB
    __shared__ unsigned int msk[kN / kJS]; // 512 B

    const int bi0 = blockIdx.x * kIPB;     // first row (b*N + i)
    const int i0 = bi0 & 255;
    const int j0 = blockIdx.y * (kN / kJS);
    const int tid = threadIdx.x;
    const int wv = tid >> 6;               // 0..15
    const int lane = tid & 63;
    const int h = lane >> 3;
    const int fg = lane & 7;

    // ---- pack adj -> LDS bitmasks: msk[jj] = 4 ii-bytes of 8 h-bits ----
    if (tid < 512) {
        const int jj = tid & 127;
        const int ii = tid >> 7;
        const int* ap = adj + (i0 + ii) * (kN * kH) + (j0 + jj) * kH;
        uint4 a0 = *(const uint4*)ap;
        uint4 a1 = *(const uint4*)(ap + 4);
        unsigned int m = 0;
        m |= (a0.x != 0) << 0; m |= (a0.y != 0) << 1;
        m |= (a0.z != 0) << 2; m |= (a0.w != 0) << 3;
        m |= (a1.x != 0) << 4; m |= (a1.y != 0) << 5;
        m |= (a1.z != 0) << 6; m |= (a1.w != 0) << 7;
        ((unsigned char*)msk)[jj * 4 + ii] = (unsigned char)m;
    }

    // ---- preload g_r[b, i0+ii, h, fg*8..+7] and attn_w as h2 ----
    h2 gri[kIPB][4];
#pragma unroll
    for (int ii = 0; ii < kIPB; ++ii) {
        uint4 pk = *(const uint4*)(gr + ((bi0 + ii) * 256 + h * 32 + fg * 4));
        H2U a0, a1, a2, a3;
        a0.u = pk.x; a1.u = pk.y; a2.u = pk.z; a3.u = pk.w;
        gri[ii][0] = a0.h; gri[ii][1] = a1.h; gri[ii][2] = a2.h; gri[ii][3] = a3.h;
    }
    h2 w2[4];
    {
        float4 wa = *(const float4*)(attn_w + fg * 8);
        float4 wb = *(const float4*)(attn_w + fg * 8 + 4);
        w2[0] = (h2){(_Float16)wa.x, (_Float16)wa.y};
        w2[1] = (h2){(_Float16)wa.z, (_Float16)wa.w};
        w2[2] = (h2){(_Float16)wb.x, (_Float16)wb.y};
        w2[3] = (h2){(_Float16)wb.z, (_Float16)wb.w};
    }

    h2 acc[kIPB][4];                       // f16 packed accumulators
#pragma unroll
    for (int ii = 0; ii < kIPB; ++ii)
#pragma unroll
        for (int q = 0; q < 4; ++q) acc[ii][q] = (h2){(_Float16)0.f, (_Float16)0.f};

    const h2 c02 = (h2){(_Float16)0.2f, (_Float16)0.2f};

    __syncthreads();                       // msk ready

    // 32-bit uint offsets; stride per j = kHF/2 = 256 uints
    unsigned int goff = (unsigned int)((bi0 >> 8) * (kN * 256)
                                       + (j0 + wv) * 256 + h * 32 + fg * 4);

    for (int it = 0; it < kN / kJS / 16; ++it) {      // 8 iters
        const int jl = wv + it * 16;                  // j_local in [0,128)
        uint4 ga = *(const uint4*)(gl + goff);
        uint4 gb = *(const uint4*)(gr + goff);
        goff += 16 * 256;
        const unsigned int m = msk[jl];               // LDS broadcast

        h2 gl2[4], gr2[4];
        { H2U t; t.u = ga.x; gl2[0] = t.h; t.u = ga.y; gl2[1] = t.h;
                 t.u = ga.z; gl2[2] = t.h; t.u = ga.w; gl2[3] = t.h;
                 t.u = gb.x; gr2[0] = t.h; t.u = gb.y; gr2[1] = t.h;
                 t.u = gb.z; gr2[2] = t.h; t.u = gb.w; gr2[3] = t.h; }

#pragma unroll
        for (int ii = 0; ii < kIPB; ++ii) {
            float e = 0.f;
#pragma unroll
            for (int q = 0; q < 4; ++q) {
                h2 s = gri[ii][q] + gl2[q];
                h2 u = __builtin_elementwise_max(s, c02 * s);  // leaky 0.2
                e = __builtin_amdgcn_fdot2(u, w2[q], e, false);
            }
            // reduce over fg (lane bits 0..2)
            e += __shfl_xor(e, 1);
            e += __shfl_xor(e, 2);
            e += __shfl_xor(e, 4);

            const unsigned int bit = (m >> (ii * 8 + h)) & 1u;
            e = bit ? e : -1e30f;

            float ex = __expf(e);
            float den = ex;
            den += __shfl_xor(den, 8);
            den += __shfl_xor(den, 16);
            den += __shfl_xor(den, 32);
            float a = ex * __builtin_amdgcn_rcpf(den);

            const h2 a2 = (h2){(_Float16)a, (_Float16)a};
#pragma unroll
            for (int q = 0; q < 4; ++q)
                acc[ii][q] = __builtin_elementwise_fma(a2, gr2[q], acc[ii][q]);
        }
    }

    // -------- two-stage cross-wave reduction (16 -> 8 -> 1), f32 in LDS ----
    if (wv >= 8) {
#pragma unroll
        for (int ii = 0; ii < kIPB; ++ii) {
            float* rp = &red[((wv - 8) * kIPB + ii) * kHF + lane * 8];
#pragma unroll
            for (int q = 0; q < 4; ++q) {
                float2 f = make_float2((float)acc[ii][q].x, (float)acc[ii][q].y);
                *(float2*)&rp[q * 2] = f;
            }
        }
    }
    __syncthreads();
    if (wv < 8) {
#pragma unroll
        for (int ii = 0; ii < kIPB; ++ii) {
            float* rp = &red[(wv * kIPB + ii) * kHF + lane * 8];
#pragma unroll
            for (int q = 0; q < 4; ++q) {
                float2 f = *(float2*)&rp[q * 2];
                f.x += (float)acc[ii][q].x;
                f.y += (float)acc[ii][q].y;
                *(float2*)&rp[q * 2] = f;
            }
        }
    }
    __syncthreads();

    // final: 2048 outputs, 1024 threads -> 2 per thread; combine via atomics
#pragma unroll
    for (int t = tid; t < kIPB * kHF; t += 1024) {
        const int ii = t >> 9;
        const int c  = t & 511;
        float s = 0.f;
#pragma unroll
        for (int w8 = 0; w8 < 8; ++w8)
            s += red[(w8 * kIPB + ii) * kHF + c];
        atomicAdd(&out[(bi0 + ii) * kHF + c], s);
    }
}

// ---------------------------------------------------------------------------
extern "C" void kernel_launch(void* const* d_in, const int* in_sizes, int n_in,
                              void* d_out, int out_size, void* d_ws, size_t ws_size,
                              hipStream_t stream) {
    const float* x  = (const float*)d_in[0];
    const float* Wl = (const float*)d_in[1];
    const float* Wr = (const float*)d_in[2];
    const float* aw = (const float*)d_in[3];
    const int* adj  = (const int*)d_in[4];

    unsigned int* gl = (unsigned int*)d_ws;                    // [B*N*HF/2]
    unsigned int* gr = gl + (size_t)kB * kN * kHF / 2;

    dim3 g1(kB * kN / 4, 2);
    gat_gemm_kernel<<<g1, 256, 0, stream>>>(x, Wl, Wr, gl, gr, (float*)d_out);

    dim3 g2(kB * kN / kIPB, kJS);
    gat_attn_kernel<<<g2, 1024, 0, stream>>>(
        gl, gr, aw, adj, (float*)d_out);
}

// Round 7
// 111.560 us; speedup vs baseline: 1.0102x; 1.0102x over previous
//
#include <hip/hip_runtime.h>
#include <hip/hip_bf16.h>

typedef _Float16 h2 __attribute__((ext_vector_type(2)));

constexpr int kB = 4, kN = 256, kC = 256, kH = 8, kF = 64, kHF = 512;
constexpr int kIPB = 2;   // attention rows (i) per block

union H2U { h2 h; unsigned int u; };

// ---------------------------------------------------------------------------
// Phase A: g = x @ W  (fp32 in, f16 out to ws). W selected by blockIdx.y.
// No LDS: x is read via block-uniform addresses (scalar loads on the SMEM
// pipe), W via per-lane float2. 256 thr = 4 rows x 512 cols. Grid (256, 2).
// ---------------------------------------------------------------------------
__global__ __launch_bounds__(256) void gat_gemm_kernel(
    const float* __restrict__ x,
    const float* __restrict__ Wl,
    const float* __restrict__ Wr,
    unsigned int* __restrict__ gl,    // f16 pairs
    unsigned int* __restrict__ gr)
{
    const int rowBase = blockIdx.x * 4;
    const float* Wm = (blockIdx.y == 0) ? Wl : Wr;
    unsigned int* gout = (blockIdx.y == 0) ? gl : gr;

    const int tid = threadIdx.x;
    const int c0 = tid * 2;           // two adjacent output cols
    const float* xr = x + rowBase * kC;

    float acc[4][2];
#pragma unroll
    for (int r = 0; r < 4; ++r) { acc[r][0] = 0.f; acc[r][1] = 0.f; }

#pragma unroll 2
    for (int k = 0; k < kC; k += 4) {
        float4 xv[4];
#pragma unroll
        for (int r = 0; r < 4; ++r)
            xv[r] = *(const float4*)(xr + r * kC + k);   // uniform -> s_load
        float2 wv[4];
#pragma unroll
        for (int kk = 0; kk < 4; ++kk)
            wv[kk] = *(const float2*)(Wm + (k + kk) * kHF + c0);
#pragma unroll
        for (int r = 0; r < 4; ++r) {
            acc[r][0] = fmaf(xv[r].x, wv[0].x, acc[r][0]);
            acc[r][1] = fmaf(xv[r].x, wv[0].y, acc[r][1]);
            acc[r][0] = fmaf(xv[r].y, wv[1].x, acc[r][0]);
            acc[r][1] = fmaf(xv[r].y, wv[1].y, acc[r][1]);
            acc[r][0] = fmaf(xv[r].z, wv[2].x, acc[r][0]);
            acc[r][1] = fmaf(xv[r].z, wv[2].y, acc[r][1]);
            acc[r][0] = fmaf(xv[r].w, wv[3].x, acc[r][0]);
            acc[r][1] = fmaf(xv[r].w, wv[3].y, acc[r][1]);
        }
    }

#pragma unroll
    for (int r = 0; r < 4; ++r) {
        H2U p; p.h = (h2){(_Float16)acc[r][0], (_Float16)acc[r][1]};
        gout[((rowBase + r) * kHF + c0) >> 1] = p.u;
    }
}

// ---------------------------------------------------------------------------
// Phase B: fused leaky-dot / head-softmax / aggregation, f16 math.
// Block = 512 threads (8 waves), 2 rows (kIPB=2), full j-range per block.
// Grid 1024 -> 4 blocks/CU = 8 waves/SIMD (VGPR <= 64, LDS 16.5 KiB).
// lane = h*8+fg; wave wv handles j = wv, wv+8, ... (32 iters).
// adj pre-packed to LDS bitmasks (1 ushort per j = 2 ii bytes x 8 h bits).
// ---------------------------------------------------------------------------
__global__ __launch_bounds__(512, 8) void gat_attn_kernel(
    const unsigned int* __restrict__ gl,   // f16 pairs
    const unsigned int* __restrict__ gr,
    const float* __restrict__ attn_w,
    const int* __restrict__ adj,
    float* __restrict__ out)
{
    __shared__ float red[4 * kIPB * kHF];       // 16 KiB
    __shared__ unsigned short msk[kN];          // 512 B

    const int bi0 = blockIdx.x * kIPB;          // first row (b*N + i)
    const int b = bi0 >> 8;
    const int i0 = bi0 & 255;
    const int tid = threadIdx.x;
    const int wv = tid >> 6;                    // 0..7
    const int lane = tid & 63;
    const int h = lane >> 3;
    const int fg = lane & 7;

    // ---- pack adj -> LDS bitmasks: msk[j] = 2 ii-bytes of 8 h-bits ----
    {
        const int jj = tid & 255;
        const int ii = tid >> 8;
        const int* ap = adj + (i0 + ii) * (kN * kH) + jj * kH;
        uint4 a0 = *(const uint4*)ap;
        uint4 a1 = *(const uint4*)(ap + 4);
        unsigned int m = 0;
        m |= (a0.x != 0) << 0; m |= (a0.y != 0) << 1;
        m |= (a0.z != 0) << 2; m |= (a0.w != 0) << 3;
        m |= (a1.x != 0) << 4; m |= (a1.y != 0) << 5;
        m |= (a1.z != 0) << 6; m |= (a1.w != 0) << 7;
        ((unsigned char*)msk)[jj * 2 + ii] = (unsigned char)m;
    }

    // ---- preload g_r[b, i0+ii, h, fg*8..+7] and attn_w as h2 ----
    h2 gri[kIPB][4];
#pragma unroll
    for (int ii = 0; ii < kIPB; ++ii) {
        uint4 pk = *(const uint4*)(gr + ((bi0 + ii) * 256 + h * 32 + fg * 4));
        H2U a0, a1, a2, a3;
        a0.u = pk.x; a1.u = pk.y; a2.u = pk.z; a3.u = pk.w;
        gri[ii][0] = a0.h; gri[ii][1] = a1.h; gri[ii][2] = a2.h; gri[ii][3] = a3.h;
    }
    h2 w2[4];
    {
        float4 wa = *(const float4*)(attn_w + fg * 8);
        float4 wb = *(const float4*)(attn_w + fg * 8 + 4);
        w2[0] = (h2){(_Float16)wa.x, (_Float16)wa.y};
        w2[1] = (h2){(_Float16)wa.z, (_Float16)wa.w};
        w2[2] = (h2){(_Float16)wb.x, (_Float16)wb.y};
        w2[3] = (h2){(_Float16)wb.z, (_Float16)wb.w};
    }

    h2 acc[kIPB][4];                       // f16 packed accumulators
#pragma unroll
    for (int ii = 0; ii < kIPB; ++ii)
#pragma unroll
        for (int q = 0; q < 4; ++q) acc[ii][q] = (h2){(_Float16)0.f, (_Float16)0.f};

    const h2 c02 = (h2){(_Float16)0.2f, (_Float16)0.2f};

    __syncthreads();                       // msk ready

    // 32-bit uint offsets; stride per j = kHF/2 = 256 uints
    unsigned int goff = (unsigned int)(b * (kN * 256) + wv * 256
                                       + h * 32 + fg * 4);

#pragma unroll 2
    for (int it = 0; it < kN / 8; ++it) {             // 32 iters
        const int j = wv + it * 8;
        uint4 ga = *(const uint4*)(gl + goff);
        uint4 gb = *(const uint4*)(gr + goff);
        goff += 8 * 256;
        const unsigned int m = msk[j];                // LDS broadcast

        h2 gl2[4], gr2[4];
        { H2U t; t.u = ga.x; gl2[0] = t.h; t.u = ga.y; gl2[1] = t.h;
                 t.u = ga.z; gl2[2] = t.h; t.u = ga.w; gl2[3] = t.h;
                 t.u = gb.x; gr2[0] = t.h; t.u = gb.y; gr2[1] = t.h;
                 t.u = gb.z; gr2[2] = t.h; t.u = gb.w; gr2[3] = t.h; }

#pragma unroll
        for (int ii = 0; ii < kIPB; ++ii) {
            float e = 0.f;
#pragma unroll
            for (int q = 0; q < 4; ++q) {
                h2 s = gri[ii][q] + gl2[q];
                h2 u = __builtin_elementwise_max(s, c02 * s);  // leaky 0.2
                e = __builtin_amdgcn_fdot2(u, w2[q], e, false);
            }
            // reduce over fg (lane bits 0..2)
            e += __shfl_xor(e, 1);
            e += __shfl_xor(e, 2);
            e += __shfl_xor(e, 4);

            const unsigned int bit = (m >> (ii * 8 + h)) & 1u;
            e = bit ? e : -1e30f;

            float ex = __expf(e);
            float den = ex;
            den += __shfl_xor(den, 8);
            den += __shfl_xor(den, 16);
            den += __shfl_xor(den, 32);
            float a = ex * __builtin_amdgcn_rcpf(den);

            const h2 a2 = (h2){(_Float16)a, (_Float16)a};
#pragma unroll
            for (int q = 0; q < 4; ++q)
                acc[ii][q] = __builtin_elementwise_fma(a2, gr2[q], acc[ii][q]);
        }
    }

    // -------- two-stage cross-wave reduction (8 -> 4 -> 1) --------
    if (wv >= 4) {
#pragma unroll
        for (int ii = 0; ii < kIPB; ++ii) {
            float* rp = &red[((wv - 4) * kIPB + ii) * kHF + lane * 8];
#pragma unroll
            for (int q = 0; q < 4; ++q) {
                float2 f = make_float2((float)acc[ii][q].x, (float)acc[ii][q].y);
                *(float2*)&rp[q * 2] = f;
            }
        }
    }
    __syncthreads();
    if (wv < 4) {
#pragma unroll
        for (int ii = 0; ii < kIPB; ++ii) {
            float* rp = &red[(wv * kIPB + ii) * kHF + lane * 8];
#pragma unroll
            for (int q = 0; q < 4; ++q) {
                float2 f = *(float2*)&rp[q * 2];
                f.x += (float)acc[ii][q].x;
                f.y += (float)acc[ii][q].y;
                *(float2*)&rp[q * 2] = f;
            }
        }
    }
    __syncthreads();

    // final: kIPB*512 = 1024 outputs, 512 threads -> 2 per thread
#pragma unroll
    for (int t = tid; t < kIPB * kHF; t += 512) {
        const int ii = t >> 9;
        const int c  = t & 511;
        float s = 0.f;
#pragma unroll
        for (int p = 0; p < 4; ++p)
            s += red[(p * kIPB + ii) * kHF + c];
        out[(bi0 + ii) * kHF + c] = s;
    }
}

// ---------------------------------------------------------------------------
extern "C" void kernel_launch(void* const* d_in, const int* in_sizes, int n_in,
                              void* d_out, int out_size, void* d_ws, size_t ws_size,
                              hipStream_t stream) {
    const float* x  = (const float*)d_in[0];
    const float* Wl = (const float*)d_in[1];
    const float* Wr = (const float*)d_in[2];
    const float* aw = (const float*)d_in[3];
    const int* adj  = (const int*)d_in[4];

    unsigned int* gl = (unsigned int*)d_ws;                    // [B*N*HF/2]
    unsigned int* gr = gl + (size_t)kB * kN * kHF / 2;

    dim3 g1(kB * kN / 4, 2);
    gat_gemm_kernel<<<g1, 256, 0, stream>>>(x, Wl, Wr, gl, gr);

    gat_attn_kernel<<<kB * kN / kIPB, 512, 0, stream>>>(
        gl, gr, aw, adj, (float*)d_out);
}